// Round 2
// baseline (7918.198 us; speedup 1.0000x reference)
//
#include <hip/hip_runtime.h>
#include <math.h>

#define HDIM 128
#define NRR  122            // computed rows/cols in the scan region
#define NSTEP 606           // wavefront steps: 4*121 + 121 + 1
#define TSTR 36             // activation row stride (floats); 144B, 16B-aligned

struct SmemMain {
  float Wt14[4][48][48];   // [layer][k][l] transposed weights, row=192B
  float Wt5[48][24];       // [k][l], row=96B
  float W6[12][24];
  float W7[12];
  float B14[4][48];
  float B5[24];
  float B6[12];
  float B7[4];             // padded so T0 stays 16B-aligned
  float T0[48][TSTR];      // original t (L1 input + L4 residual), [feature][pixel]
  float Ta[48][TSTR];
  float Tb[48][TSTR];
};

__global__ __launch_bounds__(512)
void codec_main_kernel(const float* __restrict__ x,
    const float* __restrict__ W1, const float* __restrict__ b1,
    const float* __restrict__ W2, const float* __restrict__ b2,
    const float* __restrict__ W3, const float* __restrict__ b3,
    const float* __restrict__ W4, const float* __restrict__ b4,
    const float* __restrict__ W5, const float* __restrict__ b5,
    const float* __restrict__ W6, const float* __restrict__ b6,
    const float* __restrict__ W7, const float* __restrict__ b7,
    unsigned* __restrict__ g_hist, float* __restrict__ g_sumsq,
    float* __restrict__ g_dpl)
{
  __shared__ SmemMain S;
  const int tid = threadIdx.x;
  const int plane = blockIdx.x;                       // 24 planes (b*c)
  const float* xp = x + (size_t)plane * (HDIM * HDIM);
  float* dpl = g_dpl + (size_t)plane * (NRR * HDIM);  // [122][128] abs cols

  // ---- stage transposed weights/biases to LDS, zero delta plane ----
  {
    const float* Ws[4] = {W1, W2, W3, W4};
    #pragma unroll
    for (int L = 0; L < 4; ++L)
      for (int i = tid; i < 48 * 48; i += 512)
        S.Wt14[L][i % 48][i / 48] = Ws[L][i];        // Wt[k][l] = W[l][k]
  }
  for (int i = tid; i < 24 * 48; i += 512) S.Wt5[i % 48][i / 48] = W5[i];
  for (int i = tid; i < 12 * 24; i += 512) S.W6[i / 24][i % 24] = W6[i];
  if (tid < 12) S.W7[tid] = W7[tid];
  if (tid < 48) {
    S.B14[0][tid] = b1[tid]; S.B14[1][tid] = b2[tid];
    S.B14[2][tid] = b3[tid]; S.B14[3][tid] = b4[tid];
  }
  if (tid < 24) S.B5[tid] = b5[tid];
  if (tid < 12) S.B6[tid] = b6[tid];
  if (tid == 0) S.B7[0] = b7[0];
  for (int i = tid; i < NRR * HDIM; i += 512) dpl[i] = 0.f;   // pads must be 0
  __syncthreads();

  float sumsq = 0.f;

  for (int T = 0; T < NSTEP; ++T) {
    const int r_lo = (T > 121) ? ((T - 118) >> 2) : 0;
    int r_hi = T >> 2; if (r_hi > 121) r_hi = 121;
    const int nact = r_hi - r_lo + 1;                 // <= 31

    // ---- gather t (transposed: T0[f][p]) ----
    {
      const int f = tid & 63;
      #pragma unroll
      for (int pb = 0; pb < 32; pb += 8) {
        const int p = pb + (tid >> 6);
        if (p < nact && f < 48) {
          const int r = r_lo + p, j = T - 4 * r;      // plane coords; abs=(r+3,j+3)
          float v;
          if (f < 24) {                               // x neighbors
            int row, col;
            if (f < 21) { row = r + f / 7;  col = j + f % 7; }
            else        { row = r + 3;      col = j + (f - 21); }
            v = xp[row * HDIM + col];
          } else {                                    // delta neighbors
            const int g = f - 24;
            int row, col;
            if (g < 21) { row = r - 3 + g / 7; col = j + g % 7; }
            else        { row = r;             col = j + (g - 21); }
            v = (row >= 0) ? dpl[row * HDIM + col] : 0.f;
          }
          S.T0[f][p] = v;
        }
      }
    }
    __syncthreads();

    // ---- layers 1..4: 48->48, 4x4 microtiles, k-split 2 on lane pairs ----
    {
      float (* const bufs[5])[TSTR] = {S.T0, S.Ta, S.Tb, S.Ta, S.Tb};
      #pragma unroll
      for (int L = 0; L < 4; ++L) {
        const float (*tin)[TSTR] = bufs[L];
        float (*tout)[TSTR] = bufs[L + 1];
        if (tid < 192) {
          const int ks = tid & 1, pg = (tid >> 1) & 7, lg = tid >> 4;
          const int l0 = lg * 4, p0 = pg * 4, k0 = ks * 24;
          if (p0 < nact) {
            const float* wb = &S.Wt14[L][k0][l0];
            const float* tb = &tin[k0][p0];
            float a[4][4] = {};
            #pragma unroll
            for (int k = 0; k < 24; ++k) {
              const float4 wv = *(const float4*)(wb + k * 48);
              const float4 tv = *(const float4*)(tb + k * TSTR);
              a[0][0] += wv.x * tv.x; a[0][1] += wv.x * tv.y; a[0][2] += wv.x * tv.z; a[0][3] += wv.x * tv.w;
              a[1][0] += wv.y * tv.x; a[1][1] += wv.y * tv.y; a[1][2] += wv.y * tv.z; a[1][3] += wv.y * tv.w;
              a[2][0] += wv.z * tv.x; a[2][1] += wv.z * tv.y; a[2][2] += wv.z * tv.z; a[2][3] += wv.z * tv.w;
              a[3][0] += wv.w * tv.x; a[3][1] += wv.w * tv.y; a[3][2] += wv.w * tv.z; a[3][3] += wv.w * tv.w;
            }
            #pragma unroll
            for (int i = 0; i < 4; ++i)
              #pragma unroll
              for (int jj = 0; jj < 4; ++jj)
                a[i][jj] += __shfl_xor(a[i][jj], 1);
            const int codd = (tid & 1) * 2;           // even lane: cols 0,1; odd: 2,3
            #pragma unroll
            for (int i = 0; i < 4; ++i) {
              const float bias = S.B14[L][l0 + i];
              float z0 = a[i][codd] + bias, z1 = a[i][codd + 1] + bias;
              float2 o;
              o.x = (z0 >= 0.f) ? z0 : 0.01f * z0;
              o.y = (z1 >= 0.f) ? z1 : 0.01f * z1;
              if (L == 3) {
                const float2 t0v = *(const float2*)&S.T0[l0 + i][p0 + codd];
                o.x += t0v.x; o.y += t0v.y;
              }
              *(float2*)&tout[l0 + i][p0 + codd] = o;
            }
          }
        }
        __syncthreads();
      }
    }

    // ---- L5: 48 -> 24 (Tb -> Ta), same scheme ----
    if (tid < 96) {
      const int ks = tid & 1, pg = (tid >> 1) & 7, lg = tid >> 4;  // lg 0..5
      const int l0 = lg * 4, p0 = pg * 4, k0 = ks * 24;
      if (p0 < nact) {
        const float* wb = &S.Wt5[k0][l0];
        const float* tb = &S.Tb[k0][p0];
        float a[4][4] = {};
        #pragma unroll
        for (int k = 0; k < 24; ++k) {
          const float4 wv = *(const float4*)(wb + k * 24);
          const float4 tv = *(const float4*)(tb + k * TSTR);
          a[0][0] += wv.x * tv.x; a[0][1] += wv.x * tv.y; a[0][2] += wv.x * tv.z; a[0][3] += wv.x * tv.w;
          a[1][0] += wv.y * tv.x; a[1][1] += wv.y * tv.y; a[1][2] += wv.y * tv.z; a[1][3] += wv.y * tv.w;
          a[2][0] += wv.z * tv.x; a[2][1] += wv.z * tv.y; a[2][2] += wv.z * tv.z; a[2][3] += wv.z * tv.w;
          a[3][0] += wv.w * tv.x; a[3][1] += wv.w * tv.y; a[3][2] += wv.w * tv.z; a[3][3] += wv.w * tv.w;
        }
        #pragma unroll
        for (int i = 0; i < 4; ++i)
          #pragma unroll
          for (int jj = 0; jj < 4; ++jj)
            a[i][jj] += __shfl_xor(a[i][jj], 1);
        const int codd = (tid & 1) * 2;
        #pragma unroll
        for (int i = 0; i < 4; ++i) {
          const float bias = S.B5[l0 + i];
          float z0 = a[i][codd] + bias, z1 = a[i][codd + 1] + bias;
          float2 o;
          o.x = (z0 >= 0.f) ? z0 : 0.01f * z0;
          o.y = (z1 >= 0.f) ? z1 : 0.01f * z1;
          *(float2*)&S.Ta[l0 + i][p0 + codd] = o;
        }
      }
    }
    __syncthreads();

    // ---- L6 (24->12) + L7 (12->1) fused, in-lane on wave 0 ----
    if (tid < nact) {
      const int p = tid, r = r_lo + p, j = T - 4 * r;
      float t6[24];
      #pragma unroll
      for (int k = 0; k < 24; ++k) t6[k] = S.Ta[k][p];
      float t7[12];
      #pragma unroll
      for (int l = 0; l < 12; ++l) {
        float acc = S.B6[l];
        #pragma unroll
        for (int k = 0; k < 24; ++k) acc += S.W6[l][k] * t6[k];
        t7[l] = (acc >= 0.f) ? acc : 0.01f * acc;
      }
      float acc = S.B7[0];
      #pragma unroll
      for (int k = 0; k < 12; ++k) acc += S.W7[k] * t7[k];
      const float pred = fminf(1.f, fmaxf(-1.f, acc));
      const float delta = xp[(r + 3) * HDIM + (j + 3)] - pred;
      dpl[r * HDIM + (j + 3)] = delta;
      sumsq += delta * delta;
      if (delta <= 1.0f) {             // delta >= -1 by construction; >1 excluded
        int bin = (int)((delta + 1.0f) * 128.0f);
        bin = bin > 255 ? 255 : (bin < 0 ? 0 : bin);
        atomicAdd(&g_hist[bin], 1u);
      }
    }
    __syncthreads();
  }

  // ---- flush per-block sumsq (only wave 0 accumulated) ----
  if (tid < 64) {
    float v = sumsq;
    #pragma unroll
    for (int off = 32; off; off >>= 1) v += __shfl_down(v, off);
    if (tid == 0) g_sumsq[plane] = v;
  }
}

__global__ void codec_init_kernel(unsigned* g_hist, float* g_sumsq) {
  const int t = threadIdx.x;
  if (t < 256) g_hist[t] = 0u;
  if (t < 24)  g_sumsq[t] = 0.f;
}

__global__ void codec_final_kernel(const unsigned* __restrict__ g_hist,
                                   const float* __restrict__ g_sumsq,
                                   float* __restrict__ out)
{
  __shared__ float sred[256];
  const int t = threadIdx.x;
  sred[t] = (t < 24) ? g_sumsq[t] : 0.f;
  __syncthreads();
  for (int off = 128; off; off >>= 1) {
    if (t < off) sred[t] += sred[t + off];
    __syncthreads();
  }
  const float loss = sqrtf(sred[0] / 387072.f);   // 8*3*126*128
  __syncthreads();

  // histogram entropy; bottom zero-row adds 2928 zeros -> bin 128
  const unsigned c = g_hist[t] + (t == 128 ? 2928u : 0u);
  float ent = 0.f;
  if (c) {
    const float pr = (float)c / 360144.0f;        // de.size = 24*123*122
    ent = -pr * log2f(pr);
  }
  sred[t] = ent;
  __syncthreads();
  for (int off = 128; off; off >>= 1) {
    if (t < off) sred[t] += sred[t + off];
    __syncthreads();
  }
  if (t == 0) { out[0] = loss; out[1] = sred[0] * 0.125f; }
}

extern "C" void kernel_launch(void* const* d_in, const int* in_sizes, int n_in,
                              void* d_out, int out_size, void* d_ws, size_t ws_size,
                              hipStream_t stream) {
  const float* x  = (const float*)d_in[0];
  const float* W1 = (const float*)d_in[1];  const float* b1 = (const float*)d_in[2];
  const float* W2 = (const float*)d_in[3];  const float* b2 = (const float*)d_in[4];
  const float* W3 = (const float*)d_in[5];  const float* b3 = (const float*)d_in[6];
  const float* W4 = (const float*)d_in[7];  const float* b4 = (const float*)d_in[8];
  const float* W5 = (const float*)d_in[9];  const float* b5 = (const float*)d_in[10];
  const float* W6 = (const float*)d_in[11]; const float* b6 = (const float*)d_in[12];
  const float* W7 = (const float*)d_in[13]; const float* b7 = (const float*)d_in[14];

  unsigned* g_hist = (unsigned*)d_ws;           // 256 u32
  float* g_sumsq = (float*)d_ws + 256;          // 24 f32
  float* g_dpl   = (float*)d_ws + 256 + 32;     // 24 * 122*128 f32 (~1.5 MB)

  codec_init_kernel<<<1, 256, 0, stream>>>(g_hist, g_sumsq);
  codec_main_kernel<<<24, 512, 0, stream>>>(x, W1, b1, W2, b2, W3, b3, W4, b4,
                                            W5, b5, W6, b6, W7, b7,
                                            g_hist, g_sumsq, g_dpl);
  codec_final_kernel<<<1, 256, 0, stream>>>(g_hist, g_sumsq, (float*)d_out);
}

// Round 3
// 6769.781 us; speedup vs baseline: 1.1696x; 1.1696x over previous
//
#include <hip/hip_runtime.h>
#include <math.h>

#define HDIM 128
#define NSTEP 606           // wavefront steps: 4*121 + 121 + 1
#define TSTR 36             // activation row stride (floats); 144B, 16B-aligned
#define DSTR 129            // dpl LDS row stride (floats) — odd dword => diagonal banks
#define DYN_FLOATS (122 * DSTR + 12 * 33)   // dpl + H6
#define DYN_BYTES  (DYN_FLOATS * 4)         // 64536 B

struct SmemMain {
  float Wt14[4][48][48];   // [layer][k][l] transposed weights
  float Wt5[48][24];       // [k][l]
  float W6[12][24];
  float B14[4][48];
  float B5[24];
  float B6[12];
  float W7[12];
  float B7[4];
  unsigned hist[256];
  float T0[48][TSTR];      // original t (L1 input + L4 residual), [feature][pixel]
  float Ta[48][TSTR];
  float Tb[48][TSTR];
};                          // 65360 B static

__global__ __launch_bounds__(512)
void codec_main_kernel(const float* __restrict__ x,
    const float* __restrict__ W1, const float* __restrict__ b1,
    const float* __restrict__ W2, const float* __restrict__ b2,
    const float* __restrict__ W3, const float* __restrict__ b3,
    const float* __restrict__ W4, const float* __restrict__ b4,
    const float* __restrict__ W5, const float* __restrict__ b5,
    const float* __restrict__ W6, const float* __restrict__ b6,
    const float* __restrict__ W7, const float* __restrict__ b7,
    unsigned* __restrict__ g_hist, float* __restrict__ g_sumsq)
{
  __shared__ SmemMain S;
  extern __shared__ float dyn[];
  float* dpl = dyn;                               // [122][DSTR], abs cols 0..127
  float (*H6)[33] = (float(*)[33])(dyn + 122 * DSTR);

  const int tid = threadIdx.x;
  const int plane = blockIdx.x;                   // 24 planes (b*c)
  const float* xp = x + (size_t)plane * (HDIM * HDIM);

  // ---- stage transposed weights/biases, zero hist + dpl ----
  {
    const float* Ws[4] = {W1, W2, W3, W4};
    #pragma unroll
    for (int L = 0; L < 4; ++L)
      for (int i = tid; i < 48 * 48; i += 512)
        S.Wt14[L][i % 48][i / 48] = Ws[L][i];     // Wt[k][l] = W[l][k]
  }
  for (int i = tid; i < 24 * 48; i += 512) S.Wt5[i % 48][i / 48] = W5[i];
  for (int i = tid; i < 12 * 24; i += 512) S.W6[i / 24][i % 24] = W6[i];
  if (tid < 12) S.W7[tid] = W7[tid];
  if (tid < 48) {
    S.B14[0][tid] = b1[tid]; S.B14[1][tid] = b2[tid];
    S.B14[2][tid] = b3[tid]; S.B14[3][tid] = b4[tid];
  }
  if (tid < 24) S.B5[tid] = b5[tid];
  if (tid < 12) S.B6[tid] = b6[tid];
  if (tid == 0) S.B7[0] = b7[0];
  if (tid < 256) S.hist[tid] = 0u;
  for (int i = tid; i < 122 * DSTR; i += 512) dpl[i] = 0.f;   // pads must be 0
  __syncthreads();

  float sumsq = 0.f;

  for (int T = 0; T < NSTEP; ++T) {
    const int r_lo = (T > 121) ? ((T - 118) >> 2) : 0;
    int r_hi = T >> 2; if (r_hi > 121) r_hi = 121;
    const int nact = r_hi - r_lo + 1;             // <= 31

    // ---- prefetch center x for L7 (wave 0, lane p) ----
    float xc = 0.f;
    if (tid < 32 && tid < nact) {
      const int r = r_lo + tid, j = T - 4 * r;
      xc = xp[(r + 3) * HDIM + (j + 3)];
    }

    // ---- gather t (transposed: T0[f][p]); deltas now from LDS ----
    {
      const int w8 = tid >> 6, f = tid & 63;
      if (f < 48) {
        #pragma unroll
        for (int pb = 0; pb < 32; pb += 8) {
          const int p = pb + w8;
          if (p < nact) {
            const int r = r_lo + p, j = T - 4 * r; // abs pixel = (r+3, j+3)
            float v;
            if (f < 24) {                          // x neighbors (global, cached)
              int row, col;
              if (f < 21) { row = r + f / 7;  col = j + f % 7; }
              else        { row = r + 3;      col = j + (f - 21); }
              v = xp[row * HDIM + col];
            } else {                               // delta neighbors (LDS)
              const int g = f - 24;
              int row, col;
              if (g < 21) { row = r - 3 + g / 7; col = j + g % 7; }
              else        { row = r;             col = j + (g - 21); }
              v = (row >= 0) ? dpl[row * DSTR + col] : 0.f;
            }
            S.T0[f][p] = v;
          }
        }
      }
    }
    __syncthreads();

    // ---- layers 1..4: 48->48, 4x4 microtiles, even/odd k-split on lane pairs ----
    {
      float (* const bufs[5])[TSTR] = {S.T0, S.Ta, S.Tb, S.Ta, S.Tb};
      #pragma unroll
      for (int L = 0; L < 4; ++L) {
        const float (*tin)[TSTR] = bufs[L];
        float (*tout)[TSTR] = bufs[L + 1];
        if (tid < 192) {
          const int ks = tid & 1, pg = (tid >> 1) & 7, lg = tid >> 4;
          const int l0 = lg * 4, p0 = pg * 4;
          if (p0 < nact) {
            const float* wb = &S.Wt14[L][ks][l0];   // rows 2i+ks
            const float* tb = &tin[ks][p0];
            float a[4][4] = {};
            #pragma unroll
            for (int i = 0; i < 24; ++i) {
              const float4 wv = *(const float4*)(wb + i * 96);        // 2 rows * 48
              const float4 tv = *(const float4*)(tb + i * (2 * TSTR));
              a[0][0] += wv.x * tv.x; a[0][1] += wv.x * tv.y; a[0][2] += wv.x * tv.z; a[0][3] += wv.x * tv.w;
              a[1][0] += wv.y * tv.x; a[1][1] += wv.y * tv.y; a[1][2] += wv.y * tv.z; a[1][3] += wv.y * tv.w;
              a[2][0] += wv.z * tv.x; a[2][1] += wv.z * tv.y; a[2][2] += wv.z * tv.z; a[2][3] += wv.z * tv.w;
              a[3][0] += wv.w * tv.x; a[3][1] += wv.w * tv.y; a[3][2] += wv.w * tv.z; a[3][3] += wv.w * tv.w;
            }
            #pragma unroll
            for (int i = 0; i < 4; ++i)
              #pragma unroll
              for (int jj = 0; jj < 4; ++jj)
                a[i][jj] += __shfl_xor(a[i][jj], 1);
            const int codd = (tid & 1) * 2;         // even lane: cols 0,1; odd: 2,3
            #pragma unroll
            for (int i = 0; i < 4; ++i) {
              const float bias = S.B14[L][l0 + i];
              float z0 = a[i][codd] + bias, z1 = a[i][codd + 1] + bias;
              float2 o;
              o.x = (z0 >= 0.f) ? z0 : 0.01f * z0;
              o.y = (z1 >= 0.f) ? z1 : 0.01f * z1;
              if (L == 3) {
                const float2 t0v = *(const float2*)&S.T0[l0 + i][p0 + codd];
                o.x += t0v.x; o.y += t0v.y;
              }
              *(float2*)&tout[l0 + i][p0 + codd] = o;
            }
          }
        }
        __syncthreads();
      }
    }

    // ---- L5: 48 -> 24 (Tb -> Ta) ----
    if (tid < 96) {
      const int ks = tid & 1, pg = (tid >> 1) & 7, lg = tid >> 4;  // lg 0..5
      const int l0 = lg * 4, p0 = pg * 4;
      if (p0 < nact) {
        const float* wb = &S.Wt5[ks][l0];
        const float* tb = &S.Tb[ks][p0];
        float a[4][4] = {};
        #pragma unroll
        for (int i = 0; i < 24; ++i) {
          const float4 wv = *(const float4*)(wb + i * 48);          // 2 rows * 24
          const float4 tv = *(const float4*)(tb + i * (2 * TSTR));
          a[0][0] += wv.x * tv.x; a[0][1] += wv.x * tv.y; a[0][2] += wv.x * tv.z; a[0][3] += wv.x * tv.w;
          a[1][0] += wv.y * tv.x; a[1][1] += wv.y * tv.y; a[1][2] += wv.y * tv.z; a[1][3] += wv.y * tv.w;
          a[2][0] += wv.z * tv.x; a[2][1] += wv.z * tv.y; a[2][2] += wv.z * tv.z; a[2][3] += wv.z * tv.w;
          a[3][0] += wv.w * tv.x; a[3][1] += wv.w * tv.y; a[3][2] += wv.w * tv.z; a[3][3] += wv.w * tv.w;
        }
        #pragma unroll
        for (int i = 0; i < 4; ++i)
          #pragma unroll
          for (int jj = 0; jj < 4; ++jj)
            a[i][jj] += __shfl_xor(a[i][jj], 1);
        const int codd = (tid & 1) * 2;
        #pragma unroll
        for (int i = 0; i < 4; ++i) {
          const float bias = S.B5[l0 + i];
          float z0 = a[i][codd] + bias, z1 = a[i][codd + 1] + bias;
          float2 o;
          o.x = (z0 >= 0.f) ? z0 : 0.01f * z0;
          o.y = (z1 >= 0.f) ? z1 : 0.01f * z1;
          *(float2*)&S.Ta[l0 + i][p0 + codd] = o;
        }
      }
    }
    __syncthreads();

    // ---- L6: 24 -> 12, parallel over 6 waves (l in 0..11, p in 0..31) ----
    if (tid < 384) {
      const int l = tid >> 5, p = tid & 31;
      if (p < nact) {
        float a0 = S.B6[l], a1 = 0.f;
        #pragma unroll
        for (int k = 0; k < 24; k += 2) {
          a0 += S.W6[l][k]     * S.Ta[k][p];
          a1 += S.W6[l][k + 1] * S.Ta[k + 1][p];
        }
        float z = a0 + a1;
        H6[l][p] = (z >= 0.f) ? z : 0.01f * z;
      }
    }
    __syncthreads();

    // ---- L7: 12 -> 1, clip, delta -> LDS dpl, stats (wave 0) ----
    if (tid < nact) {
      const int p = tid, r = r_lo + p, j = T - 4 * r;
      float acc = S.B7[0];
      #pragma unroll
      for (int k = 0; k < 12; ++k) acc += S.W7[k] * H6[k][p];
      const float pred = fminf(1.f, fmaxf(-1.f, acc));
      const float delta = xc - pred;
      dpl[r * DSTR + (j + 3)] = delta;
      sumsq += delta * delta;
      if (delta <= 1.0f) {             // delta >= -1 by construction; >1 excluded
        int bin = (int)((delta + 1.0f) * 128.0f);
        bin = bin > 255 ? 255 : (bin < 0 ? 0 : bin);
        atomicAdd(&S.hist[bin], 1u);
      }
    }
    __syncthreads();
  }

  // ---- flush per-block stats ----
  if (tid < 64) {
    float v = sumsq;
    #pragma unroll
    for (int off = 32; off; off >>= 1) v += __shfl_down(v, off);
    if (tid == 0) g_sumsq[plane] = v;
  }
  __syncthreads();
  if (tid < 256) {
    const unsigned c = S.hist[tid];
    if (c) atomicAdd(&g_hist[tid], c);
  }
}

__global__ void codec_init_kernel(unsigned* g_hist, float* g_sumsq) {
  const int t = threadIdx.x;
  if (t < 256) g_hist[t] = 0u;
  if (t < 24)  g_sumsq[t] = 0.f;
}

__global__ void codec_final_kernel(const unsigned* __restrict__ g_hist,
                                   const float* __restrict__ g_sumsq,
                                   float* __restrict__ out)
{
  __shared__ float sred[256];
  const int t = threadIdx.x;
  sred[t] = (t < 24) ? g_sumsq[t] : 0.f;
  __syncthreads();
  for (int off = 128; off; off >>= 1) {
    if (t < off) sred[t] += sred[t + off];
    __syncthreads();
  }
  const float loss = sqrtf(sred[0] / 387072.f);   // 8*3*126*128
  __syncthreads();

  // histogram entropy; bottom zero-row adds 2928 zeros -> bin 128
  const unsigned c = g_hist[t] + (t == 128 ? 2928u : 0u);
  float ent = 0.f;
  if (c) {
    const float pr = (float)c / 360144.0f;        // de.size = 24*123*122
    ent = -pr * log2f(pr);
  }
  sred[t] = ent;
  __syncthreads();
  for (int off = 128; off; off >>= 1) {
    if (t < off) sred[t] += sred[t + off];
    __syncthreads();
  }
  if (t == 0) { out[0] = loss; out[1] = sred[0] * 0.125f; }
}

extern "C" void kernel_launch(void* const* d_in, const int* in_sizes, int n_in,
                              void* d_out, int out_size, void* d_ws, size_t ws_size,
                              hipStream_t stream) {
  const float* x  = (const float*)d_in[0];
  const float* W1 = (const float*)d_in[1];  const float* b1 = (const float*)d_in[2];
  const float* W2 = (const float*)d_in[3];  const float* b2 = (const float*)d_in[4];
  const float* W3 = (const float*)d_in[5];  const float* b3 = (const float*)d_in[6];
  const float* W4 = (const float*)d_in[7];  const float* b4 = (const float*)d_in[8];
  const float* W5 = (const float*)d_in[9];  const float* b5 = (const float*)d_in[10];
  const float* W6 = (const float*)d_in[11]; const float* b6 = (const float*)d_in[12];
  const float* W7 = (const float*)d_in[13]; const float* b7 = (const float*)d_in[14];

  unsigned* g_hist = (unsigned*)d_ws;           // 256 u32
  float* g_sumsq = (float*)d_ws + 256;          // 24 f32

  // allow static(65360) + dynamic(64536) > 64KB on gfx950 (160KB LDS/CU)
  (void)hipFuncSetAttribute((const void*)codec_main_kernel,
                            hipFuncAttributeMaxDynamicSharedMemorySize, DYN_BYTES);

  codec_init_kernel<<<1, 256, 0, stream>>>(g_hist, g_sumsq);
  codec_main_kernel<<<24, 512, DYN_BYTES, stream>>>(x, W1, b1, W2, b2, W3, b3,
                                                    W4, b4, W5, b5, W6, b6, W7, b7,
                                                    g_hist, g_sumsq);
  codec_final_kernel<<<1, 256, 0, stream>>>(g_hist, g_sumsq, (float*)d_out);
}

// Round 5
// 5768.030 us; speedup vs baseline: 1.3728x; 1.1737x over previous
//
#include <hip/hip_runtime.h>
#include <math.h>

#define HDIM 128
#define NSTEP 606
#define NW 8                    // waves per block
#define DSTR 129                // dpl row stride (floats)

// dynamic-LDS carve (float indices)
#define O_DPL   0                          // 122*129 = 15738
#define O_W5    15740                      // 24*52 = 1248 (16B aligned)
#define O_W6    (O_W5 + 24*52)             // 12*32 = 384
#define O_T0    (O_W6 + 12*32)             // NW*192
#define O_TA    (O_T0 + NW*192)            // NW*192
#define O_HIST  (O_TA + NW*192)            // 256 u32
#define O_WRED  (O_HIST + 256)             // NW
#define DYN_FLOATS (O_WRED + NW)
#define DYN_BYTES  (DYN_FLOATS * 4)        // ~82.8 KB

template <int CTRL>
__device__ __forceinline__ float dpp_qp(float v) {
  // quad_perm DPP move (VALU pipe, no LDS)
  return __int_as_float(__builtin_amdgcn_mov_dpp(__float_as_int(v), CTRL, 0xf, 0xf, true));
}
__device__ __forceinline__ float quad_red(float v) {
  v += dpp_qp<0xB1>(v);   // quad_perm [1,0,3,2]  (xor 1)
  v += dpp_qp<0x4E>(v);   // quad_perm [2,3,0,1]  (xor 2)
  return v;
}
__device__ __forceinline__ float sel4f(float a0, float a1, float a2, float a3, int lane) {
  float m01 = (lane & 1) ? a1 : a0;
  float m23 = (lane & 1) ? a3 : a2;
  return (lane & 2) ? m23 : m01;
}
__device__ __forceinline__ int sel4i(int a0, int a1, int a2, int a3, int lane) {
  int m01 = (lane & 1) ? a1 : a0;
  int m23 = (lane & 1) ? a3 : a2;
  return (lane & 2) ? m23 : m01;
}

__global__ __launch_bounds__(512)
void codec_main_kernel(const float* __restrict__ x,
    const float* __restrict__ W1, const float* __restrict__ b1,
    const float* __restrict__ W2, const float* __restrict__ b2,
    const float* __restrict__ W3, const float* __restrict__ b3,
    const float* __restrict__ W4, const float* __restrict__ b4,
    const float* __restrict__ W5, const float* __restrict__ b5,
    const float* __restrict__ W6, const float* __restrict__ b6,
    const float* __restrict__ W7, const float* __restrict__ b7,
    unsigned* __restrict__ g_hist, float* __restrict__ g_sumsq)
{
  extern __shared__ float dyn[];
  float* dpl  = dyn + O_DPL;
  float* W5r  = dyn + O_W5;                 // [24][52]
  float* W6r  = dyn + O_W6;                 // [12][32], quarter q at col 8q
  unsigned* hist = (unsigned*)(dyn + O_HIST);
  float* wred = dyn + O_WRED;

  const int tid = threadIdx.x, wid = tid >> 6, lane = tid & 63;
  const int plane = blockIdx.x;
  const float* xp = x + (size_t)plane * (HDIM * HDIM);
  float* t0b = dyn + O_T0 + wid * 192;      // [48][4] px-packed, wave-private
  float* tab = dyn + O_TA + wid * 192;

  // ---- stage LDS weights, zero dpl/tbuf/hist/wred ----
  for (int i = tid; i < 24 * 48; i += 512) W5r[(i / 48) * 52 + (i % 48)] = W5[i];
  for (int i = tid; i < 12 * 24; i += 512) {
    int r = i / 24, k = i % 24;
    W6r[r * 32 + (k / 6) * 8 + (k % 6)] = W6[i];
  }
  for (int i = tid; i < 122 * DSTR; i += 512) dpl[i] = 0.f;
  for (int i = tid; i < NW * 384; i += 512) dyn[O_T0 + i] = 0.f;
  if (tid < 256) hist[tid] = 0u;
  if (tid < NW) wred[tid] = 0.f;

  // ---- per-lane register weights (L1-4) ----
  const int lt = lane >> 2, q = lane & 3;
  float w14[4][3][12], b14[4][3];
  {
    const float* Ws[4] = {W1, W2, W3, W4};
    const float* Bs[4] = {b1, b2, b3, b4};
    #pragma unroll
    for (int L = 0; L < 4; ++L)
      #pragma unroll
      for (int rr = 0; rr < 3; ++rr) {
        const int row = lt + 16 * rr;
        b14[L][rr] = Bs[L][row];
        #pragma unroll
        for (int kk = 0; kk < 12; ++kk) w14[L][rr][kk] = Ws[L][row * 48 + 12 * q + kk];
      }
  }
  const int lt5 = lt & 7, lt6 = lt & 3;
  float b5r[3], b6r[3], w7r[3];
  #pragma unroll
  for (int rr = 0; rr < 3; ++rr) {
    b5r[rr] = b5[lt5 + 8 * rr];
    b6r[rr] = b6[lt6 + 4 * rr];
    w7r[rr] = (lane < 16) ? W7[lt6 + 4 * rr] : 0.f;
  }
  const float B7v = b7[0];

  // ---- per-lane gather geometry ----
  const bool isx = (lane < 24) || (lane == 48);
  const bool isd = (lane >= 24 && lane < 48);
  int xro = 0, xco = 0, dro = 0, dco = 0;
  if (isx) { xro = (lane < 21) ? lane / 7 : 3; xco = (lane < 21) ? lane % 7 : (lane < 24 ? lane - 21 : 3); }
  if (isd) { const int g = lane - 24; dro = (g < 21) ? g / 7 - 3 : 0; dco = (g < 21) ? g % 7 : g - 21; }

  __syncthreads();

  float xpre[4] = {0.f, 0.f, 0.f, 0.f};
  float sumsq = 0.f;
  // initial prefetch for T=0
  #pragma unroll
  for (int p = 0; p < 4; ++p) {
    const int r = (wid & 7) + 8 * p, j = 0 - 4 * r;
    if (isx && j >= 0 && r <= 121) xpre[p] = xp[(r + xro) * HDIM + (j + xco)];
  }

  for (int T = 0; T < NSTEP; ++T) {
    const int r_lo = (T > 121) ? ((T - 118) >> 2) : 0;
    const int rbase = r_lo + ((wid - r_lo) & 7);

    int rs[4], js[4];
    bool act[4];
    float xcv[4] = {0.f, 0.f, 0.f, 0.f};
    #pragma unroll
    for (int p = 0; p < 4; ++p) {
      rs[p] = rbase + 8 * p;
      js[p] = T - 4 * rs[p];
      act[p] = (js[p] >= 0) && (rs[p] <= 121);
    }

    if (act[0]) {     // wave-uniform: any work this step?
      // ---- gather t0 (px-packed), grab xc ----
      #pragma unroll
      for (int p = 0; p < 4; ++p) {
        if (act[p]) {
          float v;
          if (isx) v = xpre[p];
          else if (isd) {
            const int drow = rs[p] + dro, dcol = js[p] + dco;
            v = (drow >= 0) ? dpl[drow * DSTR + dcol] : 0.f;
          } else v = 0.f;
          if (lane < 48) t0b[lane * 4 + p] = v;
          xcv[p] = __shfl(v, 48);
        }
      }
      // ---- prefetch x for T+1 (latency hidden under MLP) ----
      {
        const int Tn = T + 1;
        const int r_lo_n = (Tn > 121) ? ((Tn - 118) >> 2) : 0;
        const int rbase_n = r_lo_n + ((wid - r_lo_n) & 7);
        #pragma unroll
        for (int p = 0; p < 4; ++p) {
          const int rn = rbase_n + 8 * p, jn = Tn - 4 * rn;
          if (isx && jn >= 0 && rn <= 121) xpre[p] = xp[(rn + xro) * HDIM + (jn + xco)];
        }
      }

      // ---- L1-4: reg-weights, px-packed LDS activations, quad-reduce ----
      {
        const float* srcs[4] = {t0b, tab, tab, tab};
        #pragma unroll
        for (int L = 0; L < 4; ++L) {
          const float* src = srcs[L];
          float acc[3][4];
          #pragma unroll
          for (int rr = 0; rr < 3; ++rr)
            #pragma unroll
            for (int px = 0; px < 4; ++px) acc[rr][px] = 0.f;
          #pragma unroll
          for (int i = 0; i < 12; ++i) {
            const float4 tv = *(const float4*)(src + (12 * q + i) * 4);
            #pragma unroll
            for (int rr = 0; rr < 3; ++rr) {
              const float wv = w14[L][rr][i];
              acc[rr][0] += wv * tv.x; acc[rr][1] += wv * tv.y;
              acc[rr][2] += wv * tv.z; acc[rr][3] += wv * tv.w;
            }
          }
          #pragma unroll
          for (int rr = 0; rr < 3; ++rr) {
            const float s0 = quad_red(acc[rr][0]), s1 = quad_red(acc[rr][1]);
            const float s2 = quad_red(acc[rr][2]), s3 = quad_red(acc[rr][3]);
            float z = sel4f(s0, s1, s2, s3, q) + b14[L][rr];
            float o = (z >= 0.f) ? z : 0.01f * z;
            if (L == 3) o += t0b[(lt + 16 * rr) * 4 + q];
            tab[(lt + 16 * rr) * 4 + q] = o;
          }
        }
      }

      // ---- L5: 48->24, W from LDS ----
      {
        float acc[3][4];
        #pragma unroll
        for (int rr = 0; rr < 3; ++rr)
          #pragma unroll
          for (int px = 0; px < 4; ++px) acc[rr][px] = 0.f;
        float wv5[3][12];
        #pragma unroll
        for (int rr = 0; rr < 3; ++rr) {
          const float* wrow = W5r + (lt5 + 8 * rr) * 52 + 12 * q;
          #pragma unroll
          for (int i = 0; i < 12; i += 4) {
            const float4 wq = *(const float4*)(wrow + i);
            wv5[rr][i] = wq.x; wv5[rr][i+1] = wq.y; wv5[rr][i+2] = wq.z; wv5[rr][i+3] = wq.w;
          }
        }
        #pragma unroll
        for (int i = 0; i < 12; ++i) {
          const float4 tv = *(const float4*)(tab + (12 * q + i) * 4);
          #pragma unroll
          for (int rr = 0; rr < 3; ++rr) {
            const float wv = wv5[rr][i];
            acc[rr][0] += wv * tv.x; acc[rr][1] += wv * tv.y;
            acc[rr][2] += wv * tv.z; acc[rr][3] += wv * tv.w;
          }
        }
        #pragma unroll
        for (int rr = 0; rr < 3; ++rr) {
          const float s0 = quad_red(acc[rr][0]), s1 = quad_red(acc[rr][1]);
          const float s2 = quad_red(acc[rr][2]), s3 = quad_red(acc[rr][3]);
          float z = sel4f(s0, s1, s2, s3, q) + b5r[rr];
          float o = (z >= 0.f) ? z : 0.01f * z;
          if (lane < 32) tab[(lt5 + 8 * rr) * 4 + q] = o;
        }
      }

      // ---- L6 (24->12, to regs) + L7 (12->1) + delta ----
      {
        float acc[3][4];
        #pragma unroll
        for (int rr = 0; rr < 3; ++rr)
          #pragma unroll
          for (int px = 0; px < 4; ++px) acc[rr][px] = 0.f;
        #pragma unroll
        for (int i = 0; i < 6; ++i) {
          const float4 tv = *(const float4*)(tab + (6 * q + i) * 4);
          #pragma unroll
          for (int rr = 0; rr < 3; ++rr) {
            const float wv = W6r[(lt6 + 4 * rr) * 32 + 8 * q + i];
            acc[rr][0] += wv * tv.x; acc[rr][1] += wv * tv.y;
            acc[rr][2] += wv * tv.z; acc[rr][3] += wv * tv.w;
          }
        }
        float p7[4];
        #pragma unroll
        for (int px = 0; px < 4; ++px) {
          float s = 0.f;
          #pragma unroll
          for (int rr = 0; rr < 3; ++rr) {
            float z = quad_red(acc[rr][px]) + b6r[rr];
            float h = (z >= 0.f) ? z : 0.01f * z;
            s += w7r[rr] * h;
          }
          s += __shfl_xor(s, 4);
          s += __shfl_xor(s, 8);
          p7[px] = s;
        }
        if (lane < 4) {
          const bool ap = sel4i((int)act[0], (int)act[1], (int)act[2], (int)act[3], lane);
          if (ap) {
            const float pv = sel4f(p7[0], p7[1], p7[2], p7[3], lane) + B7v;
            const float xcs = sel4f(xcv[0], xcv[1], xcv[2], xcv[3], lane);
            const int rp = sel4i(rs[0], rs[1], rs[2], rs[3], lane);
            const int jp = sel4i(js[0], js[1], js[2], js[3], lane);
            const float pred = fminf(1.f, fmaxf(-1.f, pv));
            const float delta = xcs - pred;
            dpl[rp * DSTR + jp + 3] = delta;
            sumsq += delta * delta;
            if (delta <= 1.0f) {
              int bin = (int)((delta + 1.0f) * 128.0f);
              bin = bin > 255 ? 255 : (bin < 0 ? 0 : bin);
              atomicAdd(&hist[bin], 1u);
            }
          }
        }
      }
    }
    __syncthreads();
  }

  // ---- stats flush ----
  {
    float v = sumsq;
    #pragma unroll
    for (int off = 32; off; off >>= 1) v += __shfl_down(v, off);
    if (lane == 0) wred[wid] = v;
  }
  __syncthreads();
  if (tid == 0) {
    float s = 0.f;
    #pragma unroll
    for (int w = 0; w < NW; ++w) s += wred[w];
    g_sumsq[plane] = s;
  }
  if (tid < 256) {
    const unsigned c = hist[tid];
    if (c) atomicAdd(&g_hist[tid], c);
  }
}

__global__ void codec_init_kernel(unsigned* g_hist, float* g_sumsq) {
  const int t = threadIdx.x;
  if (t < 256) g_hist[t] = 0u;
  if (t < 24)  g_sumsq[t] = 0.f;
}

__global__ void codec_final_kernel(const unsigned* __restrict__ g_hist,
                                   const float* __restrict__ g_sumsq,
                                   float* __restrict__ out)
{
  __shared__ float sred[256];
  const int t = threadIdx.x;
  sred[t] = (t < 24) ? g_sumsq[t] : 0.f;
  __syncthreads();
  for (int off = 128; off; off >>= 1) {
    if (t < off) sred[t] += sred[t + off];
    __syncthreads();
  }
  const float loss = sqrtf(sred[0] / 387072.f);   // 8*3*126*128
  __syncthreads();

  const unsigned c = g_hist[t] + (t == 128 ? 2928u : 0u);  // bottom zero-row
  float ent = 0.f;
  if (c) {
    const float pr = (float)c / 360144.0f;        // 24*123*122
    ent = -pr * log2f(pr);
  }
  sred[t] = ent;
  __syncthreads();
  for (int off = 128; off; off >>= 1) {
    if (t < off) sred[t] += sred[t + off];
    __syncthreads();
  }
  if (t == 0) { out[0] = loss; out[1] = sred[0] * 0.125f; }
}

extern "C" void kernel_launch(void* const* d_in, const int* in_sizes, int n_in,
                              void* d_out, int out_size, void* d_ws, size_t ws_size,
                              hipStream_t stream) {
  const float* x  = (const float*)d_in[0];
  const float* W1 = (const float*)d_in[1];  const float* b1 = (const float*)d_in[2];
  const float* W2 = (const float*)d_in[3];  const float* b2 = (const float*)d_in[4];
  const float* W3 = (const float*)d_in[5];  const float* b3 = (const float*)d_in[6];
  const float* W4 = (const float*)d_in[7];  const float* b4 = (const float*)d_in[8];
  const float* W5 = (const float*)d_in[9];  const float* b5 = (const float*)d_in[10];
  const float* W6 = (const float*)d_in[11]; const float* b6 = (const float*)d_in[12];
  const float* W7 = (const float*)d_in[13]; const float* b7 = (const float*)d_in[14];

  unsigned* g_hist = (unsigned*)d_ws;           // 256 u32
  float* g_sumsq = (float*)d_ws + 256;          // 24 f32

  (void)hipFuncSetAttribute((const void*)codec_main_kernel,
                            hipFuncAttributeMaxDynamicSharedMemorySize, DYN_BYTES);

  codec_init_kernel<<<1, 256, 0, stream>>>(g_hist, g_sumsq);
  codec_main_kernel<<<24, 512, DYN_BYTES, stream>>>(x, W1, b1, W2, b2, W3, b3,
                                                    W4, b4, W5, b5, W6, b6, W7, b7,
                                                    g_hist, g_sumsq);
  codec_final_kernel<<<1, 256, 0, stream>>>(g_hist, g_sumsq, (float*)d_out);
}